// Round 11
// baseline (231.585 us; speedup 1.0000x reference)
//
#include <hip/hip_runtime.h>

#define B_ 16
#define L_ 512
#define H_ 256
#define V_ 32000
#define HALF_ 128

typedef __attribute__((ext_vector_type(8))) short short8;
typedef __attribute__((ext_vector_type(4))) float floatx4;
typedef __attribute__((ext_vector_type(2))) float float2v;

__device__ __forceinline__ unsigned short f2bf(float x) {
  unsigned int u = __float_as_uint(x);
  unsigned int r = (u + 0x7FFFu + ((u >> 16) & 1u)) >> 16;
  return (unsigned short)r;
}

template <int CTRL>
__device__ __forceinline__ float dpp_xor_add(float x) {
  int y = __builtin_amdgcn_mov_dpp(__float_as_int(x), CTRL, 0xf, 0xf, true);
  return x + __int_as_float(y);
}

// butterfly sum over aligned 16-lane groups; ALL lanes get the result
__device__ __forceinline__ float redu16(float p) {
  p = dpp_xor_add<0xB1>(p);   // xor1
  p = dpp_xor_add<0x4E>(p);   // xor2
  p = dpp_xor_add<0x141>(p);  // row_half_mirror
  p = dpp_xor_add<0x140>(p);  // row_mirror
  return p;
}

// packed fp32 math (VOP3P)
__device__ __forceinline__ float2v pk_fma(float2v a, float2v b, float2v c) {
  float2v d;
  asm("v_pk_fma_f32 %0, %1, %2, %3" : "=v"(d) : "v"(a), "v"(b), "v"(c));
  return d;
}
__device__ __forceinline__ float2v pk_mul(float2v a, float2v b) {
  float2v d;
  asm("v_pk_mul_f32 %0, %1, %2" : "=v"(d) : "v"(a), "v"(b));
  return d;
}

// async global->LDS copy, 16B per lane, wave-uniform LDS base
__device__ __forceinline__ void async_cp16(const float* g, float* l) {
  __builtin_amdgcn_global_load_lds(
      (const __attribute__((address_space(1))) void*)g,
      (__attribute__((address_space(3))) void*)l, 16, 0, 0);
}

// load 8 fp32, convert to 8 bf16 packed in uint4
__device__ __forceinline__ uint4 load8cvt(const float* p) {
  float4 a = ((const float4*)p)[0];
  float4 b = ((const float4*)p)[1];
  uint4 r;
  r.x = (unsigned)f2bf(a.x) | ((unsigned)f2bf(a.y) << 16);
  r.y = (unsigned)f2bf(a.z) | ((unsigned)f2bf(a.w) << 16);
  r.z = (unsigned)f2bf(b.x) | ((unsigned)f2bf(b.y) << 16);
  r.w = (unsigned)f2bf(b.z) | ((unsigned)f2bf(b.w) << 16);
  return r;
}

// ---------------- prep: weight fp32->bf16 conversion ----------------
__global__ __launch_bounds__(256) void prep_kernel(const float* __restrict__ W1,
                                                   const float* __restrict__ W2,
                                                   const float* __restrict__ Ws,
                                                   const float* __restrict__ We,
                                                   unsigned short* __restrict__ W1b,
                                                   unsigned short* __restrict__ W2b,
                                                   unsigned short* __restrict__ Wcb) {
  int i = blockIdx.x * 256 + threadIdx.x;  // 0..327679
  if (i < 131072) W1b[i] = f2bf(W1[i]);
  else if (i < 262144) W2b[i - 131072] = f2bf(W2[i - 131072]);
  else if (i < 294912) Wcb[i - 262144] = f2bf(Ws[i - 262144]);
  else Wcb[i - 262144] = f2bf(We[i - 294912]);
}

// ---------------- GEMM1: a1 = relu(embed[seq] @ W1^T + b1) -> bf16 (gather fused) ----------------
__global__ __launch_bounds__(256) void gemm1_kernel(const int* __restrict__ seq,
                                                    const float* __restrict__ embed,
                                                    const unsigned short* __restrict__ W1b,
                                                    const float* __restrict__ b1,
                                                    unsigned short* __restrict__ a1b) {
  __shared__ unsigned short As[128 * 40];
  __shared__ unsigned short Bs[128 * 40];
  int tid = threadIdx.x;
  int wave = tid >> 6, lane = tid & 63;
  int wm = (wave >> 1) * 64, wn = (wave & 1) * 64;
  int quad = lane >> 4, l15 = lane & 15;
  int bm = blockIdx.y * 128, bn = blockIdx.x * 128;
  int sr = tid >> 2, sq = tid & 3;

  int tok0 = seq[bm + sr];
  int tok1 = seq[bm + 64 + sr];

  floatx4 zero = {0.f, 0.f, 0.f, 0.f};
  floatx4 acc[4][4];
#pragma unroll
  for (int fi = 0; fi < 4; fi++)
#pragma unroll
    for (int fj = 0; fj < 4; fj++) acc[fi][fj] = zero;

  uint4 av0 = load8cvt(embed + (size_t)tok0 * H_ + sq * 8);
  uint4 av1 = load8cvt(embed + (size_t)tok1 * H_ + sq * 8);
  uint4 bv0 = *(const uint4*)(W1b + (size_t)(bn + sr) * 256 + sq * 8);
  uint4 bv1 = *(const uint4*)(W1b + (size_t)(bn + 64 + sr) * 256 + sq * 8);

  for (int k0 = 0; k0 < 256; k0 += 32) {
    __syncthreads();
    *(uint4*)(As + sr * 40 + sq * 8) = av0;
    *(uint4*)(As + (64 + sr) * 40 + sq * 8) = av1;
    *(uint4*)(Bs + sr * 40 + sq * 8) = bv0;
    *(uint4*)(Bs + (64 + sr) * 40 + sq * 8) = bv1;
    __syncthreads();
    if (k0 + 32 < 256) {
      av0 = load8cvt(embed + (size_t)tok0 * H_ + k0 + 32 + sq * 8);
      av1 = load8cvt(embed + (size_t)tok1 * H_ + k0 + 32 + sq * 8);
      bv0 = *(const uint4*)(W1b + (size_t)(bn + sr) * 256 + k0 + 32 + sq * 8);
      bv1 = *(const uint4*)(W1b + (size_t)(bn + 64 + sr) * 256 + k0 + 32 + sq * 8);
    }
    short8 af[4], bf[4];
#pragma unroll
    for (int f = 0; f < 4; f++) {
      af[f] = *(const short8*)(As + (wm + f * 16 + l15) * 40 + quad * 8);
      bf[f] = *(const short8*)(Bs + (wn + f * 16 + l15) * 40 + quad * 8);
    }
#pragma unroll
    for (int fi = 0; fi < 4; fi++)
#pragma unroll
      for (int fj = 0; fj < 4; fj++)
        acc[fi][fj] = __builtin_amdgcn_mfma_f32_16x16x32_bf16(af[fi], bf[fj], acc[fi][fj], 0, 0, 0);
  }

#pragma unroll
  for (int fi = 0; fi < 4; fi++) {
#pragma unroll
    for (int fj = 0; fj < 4; fj++) {
      int col = bn + wn + fj * 16 + l15;
      float bb = b1[col];
#pragma unroll
      for (int rg = 0; rg < 4; rg++) {
        int row = bm + wm + fi * 16 + quad * 4 + rg;
        float v = fmaxf(acc[fi][fj][rg] + bb, 0.f);
        a1b[(size_t)row * 512 + col] = f2bf(v);
      }
    }
  }
}

// ---------------- MLPK: hn = LN(a1 @ W2^T + b2 + embed[seq]) [LDS]; kproj -> khat (coalesced) + nrm ----------------
__global__ __launch_bounds__(256) void mlpk_kernel(const unsigned short* __restrict__ a1b,
                                                   const unsigned short* __restrict__ W2b,
                                                   const float* __restrict__ b2,
                                                   const int* __restrict__ seq,
                                                   const float* __restrict__ embed,
                                                   const float* __restrict__ gamma,
                                                   const float* __restrict__ beta,
                                                   const unsigned short* __restrict__ Wcb,
                                                   float* __restrict__ khat,
                                                   float* __restrict__ nrm) {
  __shared__ unsigned short As[32 * 40];
  __shared__ unsigned short Bs[256 * 40];
  __shared__ unsigned short hnS[32 * 264];
  __shared__ float stats[2][2][32];
  __shared__ float stg[2][32 * 132];  // khat staging, padded rows
  int tid = threadIdx.x;
  int wave = tid >> 6, lane = tid & 63;
  int wm = (wave >> 1) * 16, wnh = wave & 1, wn = wnh * 128;
  int quad = lane >> 4, l15 = lane & 15;
  int bm = blockIdx.x * 32;
  int sr = tid >> 2, sq = tid & 3;

  floatx4 zero = {0.f, 0.f, 0.f, 0.f};
  floatx4 acc[8];
#pragma unroll
  for (int fj = 0; fj < 8; fj++) acc[fj] = zero;

  // -------- phase 1: a1 @ W2^T, K=512 --------
  uint4 av, bv[4];
  if (tid < 128) av = *(const uint4*)(a1b + (size_t)(bm + sr) * 512 + sq * 8);
#pragma unroll
  for (int q = 0; q < 4; q++) {
    int unit = q * 256 + tid;
    bv[q] = *(const uint4*)(W2b + (size_t)(unit >> 2) * 512 + (unit & 3) * 8);
  }
  for (int k0 = 0; k0 < 512; k0 += 32) {
    __syncthreads();
    if (tid < 128) *(uint4*)(As + sr * 40 + sq * 8) = av;
#pragma unroll
    for (int q = 0; q < 4; q++) {
      int unit = q * 256 + tid;
      *(uint4*)(Bs + (unit >> 2) * 40 + (unit & 3) * 8) = bv[q];
    }
    __syncthreads();
    if (k0 + 32 < 512) {
      if (tid < 128) av = *(const uint4*)(a1b + (size_t)(bm + sr) * 512 + k0 + 32 + sq * 8);
#pragma unroll
      for (int q = 0; q < 4; q++) {
        int unit = q * 256 + tid;
        bv[q] = *(const uint4*)(W2b + (size_t)(unit >> 2) * 512 + k0 + 32 + (unit & 3) * 8);
      }
    }
    short8 af = *(const short8*)(As + (wm + l15) * 40 + quad * 8);
    short8 bf[8];
#pragma unroll
    for (int fj = 0; fj < 8; fj++)
      bf[fj] = *(const short8*)(Bs + (wn + fj * 16 + l15) * 40 + quad * 8);
#pragma unroll
    for (int fj = 0; fj < 8; fj++)
      acc[fj] = __builtin_amdgcn_mfma_f32_16x16x32_bf16(af, bf[fj], acc[fj], 0, 0, 0);
  }

  // -------- LN epilogue -> hnS (LDS) --------
  int seqv[4];
#pragma unroll
  for (int rg = 0; rg < 4; rg++) seqv[rg] = seq[bm + wm + quad * 4 + rg];
  float v[8][4];
#pragma unroll
  for (int fj = 0; fj < 8; fj++) {
    int col = wn + fj * 16 + l15;
    float bb = b2[col];
#pragma unroll
    for (int rg = 0; rg < 4; rg++)
      v[fj][rg] = acc[fj][rg] + bb + embed[(size_t)seqv[rg] * H_ + col];
  }
  float s_[4], q_[4];
#pragma unroll
  for (int rg = 0; rg < 4; rg++) {
    float s = 0.f, q = 0.f;
#pragma unroll
    for (int fj = 0; fj < 8; fj++) {
      s += v[fj][rg];
      q += v[fj][rg] * v[fj][rg];
    }
    s_[rg] = redu16(s);
    q_[rg] = redu16(q);
  }
  if (l15 == 0) {
#pragma unroll
    for (int rg = 0; rg < 4; rg++) {
      int rlocal = wm + quad * 4 + rg;
      stats[wnh][0][rlocal] = s_[rg];
      stats[wnh][1][rlocal] = q_[rg];
    }
  }
  __syncthreads();
#pragma unroll
  for (int rg = 0; rg < 4; rg++) {
    int rlocal = wm + quad * 4 + rg;
    float sum = stats[0][0][rlocal] + stats[1][0][rlocal];
    float ssq = stats[0][1][rlocal] + stats[1][1][rlocal];
    float mu = sum * (1.f / H_);
    float var = ssq * (1.f / H_) - mu * mu;
    float inv = rsqrtf(var + 1e-5f);
#pragma unroll
    for (int fj = 0; fj < 8; fj++) {
      int col = wn + fj * 16 + l15;
      float y = (v[fj][rg] - mu) * inv * gamma[col] + beta[col];
      hnS[rlocal * 264 + col] = f2bf(y);
    }
  }
  __syncthreads();

  // -------- phase 2: kproj, K=256, A from hnS --------
  floatx4 acc2[8];
#pragma unroll
  for (int fj = 0; fj < 8; fj++) acc2[fj] = zero;
#pragma unroll
  for (int q = 0; q < 4; q++) {
    int unit = q * 256 + tid;
    bv[q] = *(const uint4*)(Wcb + (size_t)(unit >> 2) * 256 + (unit & 3) * 8);
  }
  for (int k0 = 0; k0 < 256; k0 += 32) {
    __syncthreads();
#pragma unroll
    for (int q = 0; q < 4; q++) {
      int unit = q * 256 + tid;
      *(uint4*)(Bs + (unit >> 2) * 40 + (unit & 3) * 8) = bv[q];
    }
    __syncthreads();
    if (k0 + 32 < 256) {
#pragma unroll
      for (int q = 0; q < 4; q++) {
        int unit = q * 256 + tid;
        bv[q] = *(const uint4*)(Wcb + (size_t)(unit >> 2) * 256 + k0 + 32 + (unit & 3) * 8);
      }
    }
    short8 af = *(const short8*)(hnS + (wm + l15) * 264 + k0 + quad * 8);
    short8 bf[8];
#pragma unroll
    for (int fj = 0; fj < 8; fj++)
      bf[fj] = *(const short8*)(Bs + (wn + fj * 16 + l15) * 40 + quad * 8);
#pragma unroll
    for (int fj = 0; fj < 8; fj++)
      acc2[fj] = __builtin_amdgcn_mfma_f32_16x16x32_bf16(af, bf[fj], acc2[fj], 0, 0, 0);
  }

  // -------- norm epilogue: nrm + khat (permuted cols) staged in LDS, coalesced global write --------
  int b = bm >> 9;
  int idxm = b * 2 + wnh;
  int tloc0 = (bm & 511) + wm + quad * 4;
  float inv[4], nr4[4];
#pragma unroll
  for (int rg = 0; rg < 4; rg++) {
    float ssq = 0.f;
#pragma unroll
    for (int fj = 0; fj < 8; fj++) ssq += acc2[fj][rg] * acc2[fj][rg];
    ssq = redu16(ssq);
    nr4[rg] = fmaxf(sqrtf(ssq), 1e-12f);
    inv[rg] = 1.f / nr4[rg];
  }
  if (l15 == 0) {
#pragma unroll
    for (int rg = 0; rg < 4; rg++) nrm[(size_t)idxm * L_ + tloc0 + rg] = nr4[rg];
  }
#pragma unroll
  for (int fj = 0; fj < 8; fj++) {
    int ch = fj * 16 + l15;             // logical col 0..127
    int j = ch >> 2, e = ch & 3;
    int pj = (j & 1) ? (16 + (j >> 1)) : (j >> 1);  // even granules first
    int pcol = pj * 4 + e;
    int trl = wm + quad * 4;
#pragma unroll
    for (int rg = 0; rg < 4; rg++)
      stg[wnh][(trl + rg) * 132 + pcol] = acc2[fj][rg] * inv[rg];
  }
  __syncthreads();
  // coalesced: 2 halves x 32 rows x 128 cols = 2048 float4, 8 per thread
#pragma unroll
  for (int f = 0; f < 8; f++) {
    int idx = f * 256 + tid;
    int w = idx >> 10, rem = idx & 1023;
    int tr = rem >> 5, l = rem & 31;
    float4 vv = *(float4*)&stg[w][tr * 132 + l * 4];
    int im = (bm >> 9) * 2 + w;
    *(float4*)&khat[((size_t)im * L_ + (bm & 511) + tr) * HALF_ + l * 4] = vv;
  }
}

// ---------------- scan: LDS-staged khat, packed-fp32 step, kr reconstructed from khat*nrm ----------------
#define STEP(KP, KH, NR)                                                 \
  do {                                                                   \
    float2v t_ = pk_mul(m01, KP[0]);                                     \
    t_ = pk_fma(m23, KP[1], t_);                                         \
    t_ = pk_fma(m45, KP[2], t_);                                         \
    t_ = pk_fma(m67, KP[3], t_);                                         \
    float p_ = t_.x + t_.y;                                              \
    p_ = redu16(p_);                                                     \
    float sv_ = (KH) * (NR)-p_;                                          \
    float2v s2_ = {sv_, sv_};                                            \
    m01 = pk_fma(s2_, KP[0], m01);                                       \
    m23 = pk_fma(s2_, KP[1], m23);                                       \
    m45 = pk_fma(s2_, KP[2], m45);                                       \
    m67 = pk_fma(s2_, KP[3], m67);                                       \
  } while (0)

#define LOADPK(DST, PTR)                                                 \
  do {                                                                   \
    float4 a_ = *(const float4*)(PTR);                                   \
    float4 b_ = *(const float4*)((PTR) + 64);                            \
    DST[0] = (float2v){a_.x, a_.y};                                      \
    DST[1] = (float2v){a_.z, a_.w};                                      \
    DST[2] = (float2v){b_.x, b_.y};                                      \
    DST[3] = (float2v){b_.z, b_.w};                                      \
  } while (0)

__global__ __launch_bounds__(256) void scan_kernel(const float* __restrict__ khat,
                                                   const float* __restrict__ nrm,
                                                   float* __restrict__ c) {
  __shared__ float sk[2][64 * 128];  // 2 x 32 KB double buffer
  int bid = blockIdx.x;
  int idxm = bid & 31;
  int rg = bid >> 5;
  int b = idxm >> 1, mat = idxm & 1;
  const float* kh = khat + (size_t)idxm * L_ * HALF_;
  const float* np = nrm + (size_t)idxm * L_;

  int tid = threadIdx.x;
  int wave = tid >> 6, lane = tid & 63;
  int seg = tid & 15, rl = tid >> 4;
  int r = rg * 16 + rl;
  // permuted position of logical row r within a stored khat row
  int jj = r >> 2, ee = r & 3;
  int pj = (jj & 1) ? (16 + (jj >> 1)) : (jj >> 1);
  int prow = pj * 4 + ee;

  float2v m01 = {0.f, 0.f}, m23 = {0.f, 0.f}, m45 = {0.f, 0.f}, m67 = {0.f, 0.f};

  // stage chunk 0 into buf 0
#pragma unroll
  for (int j = 0; j < 8; j++)
    async_cp16(kh + wave * 2048 + j * 256 + lane * 4, &sk[0][wave * 2048 + j * 256] + lane * 4);
  __syncthreads();

  float4 nrn = *(const float4*)(np);  // norms, steps 0..3
  const float* lb = &sk[0][0] + seg * 4;
  const float* lk = &sk[0][0] + prow;

  // chunks 0..6 (full 64 steps each)
  for (int ch = 0; ch < 7; ch++) {
#pragma unroll
    for (int j = 0; j < 8; j++)
      async_cp16(kh + (size_t)(ch + 1) * 8192 + wave * 2048 + j * 256 + lane * 4,
                 &sk[(ch + 1) & 1][wave * 2048 + j * 256] + lane * 4);
    const float* base = lb + (ch & 1) * 8192;
    const float* kb2 = lk + (ch & 1) * 8192;
    float2v pk[4][4];
    float kh4[4];
#pragma unroll
    for (int u = 0; u < 4; u++) {
      LOADPK(pk[u], base + u * 128);
      kh4[u] = kb2[u * 128];
    }
    for (int g = 0; g < 15; g++) {
      float4 nrc = nrn;
      nrn = *(const float4*)(np + ch * 64 + g * 4 + 4);
#pragma unroll
      for (int u = 0; u < 4; u++) {
        STEP(pk[u], kh4[u], ((u == 0) ? nrc.x : (u == 1) ? nrc.y : (u == 2) ? nrc.z : nrc.w));
        int tn = g * 4 + u + 4;
        LOADPK(pk[u], base + tn * 128);
        kh4[u] = kb2[tn * 128];
      }
    }
    {
      float4 nrc = nrn;
      nrn = *(const float4*)(np + ch * 64 + 64);
      STEP(pk[0], kh4[0], nrc.x);
      STEP(pk[1], kh4[1], nrc.y);
      STEP(pk[2], kh4[2], nrc.z);
      STEP(pk[3], kh4[3], nrc.w);
    }
    __syncthreads();
  }

  // chunk 7: steps 448..510, then query t=511 (left in pk[3])
  {
    const float* base = lb + 8192;
    const float* kb2 = lk + 8192;
    float2v pk[4][4];
    float kh4[4];
#pragma unroll
    for (int u = 0; u < 4; u++) {
      LOADPK(pk[u], base + u * 128);
      kh4[u] = kb2[u * 128];
    }
    for (int g = 0; g < 15; g++) {
      float4 nrc = nrn;
      nrn = *(const float4*)(np + 448 + g * 4 + 4);
#pragma unroll
      for (int u = 0; u < 4; u++) {
        STEP(pk[u], kh4[u], ((u == 0) ? nrc.x : (u == 1) ? nrc.y : (u == 2) ? nrc.z : nrc.w));
        int tn = g * 4 + u + 4;
        LOADPK(pk[u], base + tn * 128);
        kh4[u] = kb2[tn * 128];
      }
    }
    float4 nrc = nrn;    // norms for 508..511
    STEP(pk[0], kh4[0], nrc.x);  // 508
    STEP(pk[1], kh4[1], nrc.y);  // 509
    STEP(pk[2], kh4[2], nrc.z);  // 510
    // final read: q = khat[511] * nrm[511]; dot(M, q) = nrm511 * dot(m, khat511)
    float2v tq = pk_mul(m01, pk[3][0]);
    tq = pk_fma(m23, pk[3][1], tq);
    tq = pk_fma(m45, pk[3][2], tq);
    tq = pk_fma(m67, pk[3][3], tq);
    float p = redu16(tq.x + tq.y) * nrc.w;
    if (seg == 0) c[(size_t)b * H_ + mat * HALF_ + r] = p;
  }
}

// ---------------- r = c @ W_rp^T + b_rp ----------------
__global__ void rp_kernel(const float* __restrict__ c, const float* __restrict__ Wrp,
                          const float* __restrict__ brp, float* __restrict__ r) {
  int b = blockIdx.x;
  int n = threadIdx.x;  // 256
  __shared__ float cs[H_];
  cs[n] = c[(size_t)b * H_ + n];
  __syncthreads();
  const float4* w4 = (const float4*)(Wrp + (size_t)n * H_);
  const float4* c4 = (const float4*)cs;
  float acc = 0.f;
#pragma unroll 8
  for (int k = 0; k < H_ / 4; k++) {
    float4 w = w4[k], cc = c4[k];
    acc += w.x * cc.x + w.y * cc.y + w.z * cc.z + w.w * cc.w;
  }
  r[(size_t)b * H_ + n] = acc + brp[n];
}

// ---------------- out = r @ W_out^T + b_out, coalesced ----------------
__global__ __launch_bounds__(256) void out_kernel(const float* __restrict__ r,
                                                  const float* __restrict__ Wout,
                                                  const float* __restrict__ bout,
                                                  float* __restrict__ out) {
  __shared__ float rs[16 * 272];
  __shared__ float obuf[16 * 68];
  int tid = threadIdx.x;
#pragma unroll
  for (int q = 0; q < 16; q++) {
    int idx = q * 256 + tid;
    int bb = idx >> 8, cc = idx & 255;
    rs[bb * 272 + cc + 4 * (cc >> 6)] = r[idx];
  }
  __syncthreads();
  int row = tid >> 2, part = tid & 3;
  int v = blockIdx.x * 64 + row;
  const float4* w4 = (const float4*)(Wout + (size_t)v * H_ + part * 64);
  float acc[16];
#pragma unroll
  for (int bb = 0; bb < 16; bb++) acc[bb] = 0.f;
#pragma unroll 4
  for (int j = 0; j < 16; j++) {
    float4 w = w4[j];
#pragma unroll
    for (int bb = 0; bb < 16; bb++) {
      float4 rv = *(const float4*)&rs[bb * 272 + part * 68 + j * 4];
      acc[bb] += w.x * rv.x + w.y * rv.y + w.z * rv.z + w.w * rv.w;
    }
  }
  float bo = bout[v];
#pragma unroll
  for (int bb = 0; bb < 16; bb++) {
    acc[bb] = dpp_xor_add<0xB1>(acc[bb]);
    acc[bb] = dpp_xor_add<0x4E>(acc[bb]);
  }
#pragma unroll
  for (int q = 0; q < 4; q++) {
    int bb = part * 4 + q;
    obuf[bb * 68 + row] = acc[bb] + bo;
  }
  __syncthreads();
#pragma unroll
  for (int q = 0; q < 4; q++) {
    int idx = q * 256 + tid;
    int bb = idx >> 6, vl = idx & 63;
    out[(size_t)bb * V_ + blockIdx.x * 64 + vl] = obuf[bb * 68 + vl];
  }
}

extern "C" void kernel_launch(void* const* d_in, const int* in_sizes, int n_in,
                              void* d_out, int out_size, void* d_ws, size_t ws_size,
                              hipStream_t stream) {
  const int* seq = (const int*)d_in[0];
  const float* embed = (const float*)d_in[1];
  const float* W1 = (const float*)d_in[2];
  const float* b1 = (const float*)d_in[3];
  const float* W2 = (const float*)d_in[4];
  const float* b2 = (const float*)d_in[5];
  const float* gamma = (const float*)d_in[6];
  const float* beta = (const float*)d_in[7];
  const float* Wsem = (const float*)d_in[8];
  const float* Wepi = (const float*)d_in[9];
  const float* Wrp = (const float*)d_in[10];
  const float* brp = (const float*)d_in[11];
  const float* Wout = (const float*)d_in[12];
  const float* bout = (const float*)d_in[13];
  float* out = (float*)d_out;

  // Workspace (float-slot offsets), disjoint:
  //  [0       , 2097152)  a1b bf16 [8192,512]
  //  [2097152 , 4194304)  khat fp32 [32,512,128]
  //  [4194304 , 4210688)  nrm  fp32 [32,512]
  //  [4210688 , 4276224)  W1b bf16 131072
  //  [4276224 , 4341760)  W2b bf16 131072
  //  [4341760 , 4374528)  Wcb bf16 65536
  //  [4374528 , 4378624)  c [16,256]
  //  [4378624 , 4382720)  r [16,256]
  float* ws = (float*)d_ws;
  unsigned short* a1b = (unsigned short*)ws;
  float* khat = ws + 2097152;
  float* nrm = ws + 4194304;
  unsigned short* W1b = (unsigned short*)(ws + 4210688);
  unsigned short* W2b = (unsigned short*)(ws + 4276224);
  unsigned short* Wcb = (unsigned short*)(ws + 4341760);
  float* c = ws + 4374528;
  float* r = ws + 4378624;

  // 1. weights -> bf16
  prep_kernel<<<1280, 256, 0, stream>>>(W1, W2, Wsem, Wepi, W1b, W2b, Wcb);
  // 2. a1 = relu(embed[seq] @ W1^T + b1) -> bf16
  gemm1_kernel<<<dim3(4, 64), 256, 0, stream>>>(seq, embed, W1b, b1, a1b);
  // 3. hn = LN(a1 @ W2^T + b2 + embed[seq]) [LDS]; kproj + normalize -> khat (coalesced) + nrm
  mlpk_kernel<<<256, 256, 0, stream>>>(a1b, W2b, b2, seq, embed, gamma, beta, Wcb, khat, nrm);
  // 4. delta-rule scan -> c [16,256]
  scan_kernel<<<256, 256, 0, stream>>>(khat, nrm, c);
  // 5. r = c @ Wrp^T + brp
  rp_kernel<<<16, 256, 0, stream>>>(c, Wrp, brp, r);
  // 6. out = r @ Wout^T + bout
  out_kernel<<<500, 256, 0, stream>>>(r, Wout, bout, out);
}